// Round 8
// baseline (174.078 us; speedup 1.0000x reference)
//
#include <hip/hip_runtime.h>
#include <hip/hip_fp16.h>

// x: (2,8,256,256) fp32, F: 3x3 fp32.
#define HS 256
#define WSZ 256
#define NPIX (HS * WSZ)        // 65536 pixels
#define NCH 16                 // B*C
#define NELEM (NPIX * NCH)     // half elements in T

typedef float f4 __attribute__((ext_vector_type(4)));

// ---------------------------------------------------------------------------
// Transpose + fp16 quantize: (bc, h, w) f32 -> (h, w, bc) f16, LDS-tiled,
// coalesced both sides. Also zeroes a 512 B pad at T[NELEM..).
// ---------------------------------------------------------------------------
__global__ __launch_bounds__(256) void transpose_f16(const float* __restrict__ x,
                                                     __half* __restrict__ T) {
    __shared__ float lds[16][257];   // +1 pad
    int tid  = threadIdx.x;
    int base = blockIdx.x * 256;
#pragma unroll
    for (int ch = 0; ch < 16; ++ch)
        lds[ch][tid] = x[ch * NPIX + base + tid];   // coalesced 1KB per instr
    if (blockIdx.x == 0 && tid < 128)
        ((unsigned int*)(T + NELEM))[tid] = 0u;     // 512 B zero pad
    __syncthreads();
    uint2* T2 = (uint2*)T;           // 8 B = 4 halves = one channel-quad
#pragma unroll
    for (int it = 0; it < 4; ++it) {
        int idx = it * 256 + tid;    // 0..1023 uint2 of this tile
        int p   = idx >> 2;          // local pixel
        int q   = idx & 3;           // channel quad
        __half2 a = __floats2half2_rn(lds[q * 4 + 0][p], lds[q * 4 + 1][p]);
        __half2 b = __floats2half2_rn(lds[q * 4 + 2][p], lds[q * 4 + 3][p]);
        uint2 o;
        o.x = __builtin_bit_cast(unsigned int, a);
        o.y = __builtin_bit_cast(unsigned int, b);
        T2[base * 4 + idx] = o;      // contiguous 8B/lane -> coalesced
    }
}

// ---------------------------------------------------------------------------
// Geometry (bit-exact, verified): FMA-contracted einsum, f32. UNCHANGED.
// ---------------------------------------------------------------------------
struct LineGeom {
    float p, q, c;
    bool  col;
};

__device__ __forceinline__ LineGeom make_geom(const float* __restrict__ F, int pix) {
#pragma clang fp contract(off)
    int w = pix & (WSZ - 1);
    int h = pix >> 8;
    float u = (float)w, v = (float)h;
    float a = __builtin_fmaf(F[3], v, F[0] * u) + F[6];
    float b = __builtin_fmaf(F[4], v, F[1] * u) + F[7];
    float c = __builtin_fmaf(F[5], v, F[2] * u) + F[8];
    const float eps = 1e-8f;
    float bs = (fabsf(b) < eps) ? eps : b;
    float as = (fabsf(a) < eps) ? eps : a;
    LineGeom g;
    g.col = (fabsf(b) >= fabsf(a));
    g.p   = g.col ? a : b;
    g.q   = g.col ? bs : as;
    g.c   = c;
    return g;
}

// Exact chain (reference-bit-exact): t = fma(p,s,c); y = (-t)/q IEEE; rint.
__device__ __forceinline__ int chainY(const LineGeom& g, int s) {
#pragma clang fp contract(off)
    float t  = __builtin_fmaf(g.p, (float)s, g.c);
    float y  = (-t) / g.q;
    return (int)__builtin_rintf(y);
}

// Fast chain (verified R5-pass): rcp + Newton + Markstein; half-integer guard
// band 2e-4 redirects to the IEEE divide -> rint bit-identical to chainY.
__device__ __forceinline__ int chainY_fast(const LineGeom& g, float rq, int s) {
#pragma clang fp contract(off)
    float num = __builtin_fmaf(-g.p, (float)s, -g.c);   // == -fma(p,s,c) exactly
    float y0  = num * rq;
    float e   = __builtin_fmaf(-g.q, y0, num);
    float y1  = __builtin_fmaf(e, rq, y0);
    float fr  = y1 - floorf(y1);
    if (__builtin_expect(fabsf(fr - 0.5f) < 2e-4f, 0))
        y1 = num / g.q;                                  // exact IEEE fallback
    return (int)__builtin_rintf(y1);
}

__device__ __forceinline__ __half2 bch2(unsigned int v) {
    return __builtin_bit_cast(__half2, v);
}

// DPP rotate-add within the 16-lane row (wait-free VALU).
template <int CTRL>
__device__ __forceinline__ float dpp_ror_add(float v) {
    int t = __builtin_amdgcn_mov_dpp(__builtin_bit_cast(int, v), CTRL, 0xf, 0xf, true);
    return v + __builtin_bit_cast(float, t);
}

template <int CTRL>
__device__ __forceinline__ void ror_add8(f4& a0, f4& a1) {
    a0.x = dpp_ror_add<CTRL>(a0.x);
    a0.y = dpp_ror_add<CTRL>(a0.y);
    a0.z = dpp_ror_add<CTRL>(a0.z);
    a0.w = dpp_ror_add<CTRL>(a0.w);
    a1.x = dpp_ror_add<CTRL>(a1.x);
    a1.y = dpp_ror_add<CTRL>(a1.y);
    a1.z = dpp_ror_add<CTRL>(a1.z);
    a1.w = dpp_ror_add<CTRL>(a1.w);
}

// ---------------------------------------------------------------------------
// Gather v5 body, INSTRUMENTED (this round is a measurement round):
//   REP    — repeat the whole gather in-kernel so the dispatch crosses the
//            42 us fill cutoff and shows up in the PMC table (idempotent
//            output; memory clobber between reps forces real re-loads).
//   NOLOAD — redirect every load to the fixed pad address while keeping the
//            address math alive (inline-asm, rule #17) => pure VALU/issue
//            floor with near-zero memory latency. Output garbage; the real
//            (NOLOAD=false) launch runs LAST and overwrites everything.
// Mapping (verified): 16 lanes/pixel = 8 sample-slots x 2 channel-halves;
// lane r=2k+h loads 16 B (8 ch, half h) of s = 8m+k; pixel's 16 lanes cover
// 8 consecutive samples = 256 B contiguous per load instr.
// ---------------------------------------------------------------------------
#define QUAD_BCAST(dst, src, ctrl)                                              \
    dst = __builtin_amdgcn_mov_dpp(src, ctrl, 0xf, 0xf, false)

template <int REP, bool NOLOAD>
__global__ __launch_bounds__(256) void epi_gather_f16(const uint4* __restrict__ Tq,
                                                      const float* __restrict__ x,
                                                      const float* __restrict__ F,
                                                      float* __restrict__ out) {
    int tid = blockIdx.x * 256 + threadIdx.x;
    int r   = tid & 15;          // lane-in-pixel, r = 2k + h
    int k   = r >> 1;            // sample phase: s ≡ k (mod 8)
    int h   = r & 1;             // channel half: ch 8h..8h+7
    int pix = tid >> 4;

    LineGeom g = make_geom(F, pix);
    // per-pixel reciprocal for the fast chain (1 rcp + 1 NR step)
    float r0 = __builtin_amdgcn_rcpf(g.q);
    float rq = __builtin_fmaf(__builtin_fmaf(-g.q, r0, 1.0f), r0, r0);

#pragma unroll 1
    for (int rep = 0; rep < REP; ++rep) {
        asm volatile("" ::: "memory");   // force re-load of T each rep
        f4 a0 = {0.f, 0.f, 0.f, 0.f};
        f4 a1 = {0.f, 0.f, 0.f, 0.f};

        if (g.col) {
            const int PADB = NPIX * 2;      // T size in 16B units (= 131072)
            int  padr = PADB + r;           // zero-pad slot for this lane
            int  rb   = r;                  // r + 128*b, incremented per batch
            bool hb   = (h != 0);
            int  sb   = (h << 5) + k;       // own chains: s = sb + 64b + 8i

#pragma unroll
            for (int bb = 0; bb < 2; ++bb) {
                // f16 partials live across TWO batches (16 samples per slot)
                __half2 zz = __floats2half2_rn(0.f, 0.f);
                __half2 s0 = zz, s1 = zz, s2 = zz, s3 = zz;

#pragma unroll
                for (int b2 = 0; b2 < 2; ++b2) {
                    int b = 2 * bb + b2;
                    // 4 own chains (jj = 4h+i), then swap with pair lane
                    int yown[4], yswp[4];
#pragma unroll
                    for (int i = 0; i < 4; ++i)
                        yown[i] = chainY_fast(g, rq, sb + 64 * b + 8 * i);
#pragma unroll
                    for (int i = 0; i < 4; ++i) QUAD_BCAST(yswp[i], yown[i], 0xB1);

                    int adr[8];
#pragma unroll
                    for (int i = 0; i < 4; ++i) {
                        int ylo = hb ? yswp[i] : yown[i];   // chain of j = i
                        int yhi = hb ? yown[i] : yswp[i];   // chain of j = i+4
                        int alo = (int)((unsigned)ylo << 9) + rb;
                        int ahi = (int)((unsigned)yhi << 9) + rb;
                        adr[i]     = ((unsigned)ylo < 256u) ? alo : (padr - 16 * i);
                        adr[i + 4] = ((unsigned)yhi < 256u) ? ahi : (padr - 16 * (i + 4));
                    }
                    if (NOLOAD) {
                        // keep the address math alive, then aim every load at
                        // the pad => zero-latency memory, identical VALU.
#pragma unroll
                        for (int j = 0; j < 8; ++j) {
                            int t = adr[j];
                            asm volatile("" : "+v"(t));
                            adr[j] = padr;
                        }
                    }
                    // batch-issue 8 independent 16B loads; +16j folds into imm
                    uint4 v0 = Tq[adr[0] +   0];
                    uint4 v1 = Tq[adr[1] +  16];
                    uint4 v2 = Tq[adr[2] +  32];
                    uint4 v3 = Tq[adr[3] +  48];
                    uint4 v4 = Tq[adr[4] +  64];
                    uint4 v5 = Tq[adr[5] +  80];
                    uint4 v6 = Tq[adr[6] +  96];
                    uint4 v7 = Tq[adr[7] + 112];

#define ACC(V)                                                                  \
                    s0 = __hadd2(s0, bch2((V).x));                              \
                    s1 = __hadd2(s1, bch2((V).y));                              \
                    s2 = __hadd2(s2, bch2((V).z));                              \
                    s3 = __hadd2(s3, bch2((V).w));
                    ACC(v0) ACC(v1) ACC(v2) ACC(v3) ACC(v4) ACC(v5) ACC(v6) ACC(v7)
#undef ACC
                    rb += 128;
                }
                // fold the 2-batch f16 partials into f32 accumulators
                float2 f;
                f = __half22float2(s0); a0.x += f.x; a0.y += f.y;
                f = __half22float2(s1); a0.z += f.x; a0.w += f.y;
                f = __half22float2(s2); a1.x += f.x; a1.y += f.y;
                f = __half22float2(s3); a1.z += f.x; a1.w += f.y;
            }
        } else {
            // Row mode (never taken for this F; generic correctness).
            int ch0 = h * 8;
            for (int m = 0; m < 32; ++m) {
                int s  = 8 * m + k;
                int xi = chainY(g, s);
                if ((unsigned)xi < 256u) {
                    int addr = s * WSZ + xi;
                    a0.x += x[(ch0 + 0) * NPIX + addr];
                    a0.y += x[(ch0 + 1) * NPIX + addr];
                    a0.z += x[(ch0 + 2) * NPIX + addr];
                    a0.w += x[(ch0 + 3) * NPIX + addr];
                    a1.x += x[(ch0 + 4) * NPIX + addr];
                    a1.y += x[(ch0 + 5) * NPIX + addr];
                    a1.z += x[(ch0 + 6) * NPIX + addr];
                    a1.w += x[(ch0 + 7) * NPIX + addr];
                }
            }
        }

        // reduce over the 8 sample-slots: DPP row_ror 8,4,2
        ror_add8<0x128>(a0, a1);   // row_ror:8
        ror_add8<0x124>(a0, a1);   // row_ror:4
        ror_add8<0x122>(a0, a1);   // row_ror:2

        if ((r & 14) == 0) {             // lanes r=0 (ch 0-7) and r=1 (ch 8-15)
            int ch0 = h * 8;
            out[(ch0 + 0) * NPIX + pix] = a0.x;
            out[(ch0 + 1) * NPIX + pix] = a0.y;
            out[(ch0 + 2) * NPIX + pix] = a0.z;
            out[(ch0 + 3) * NPIX + pix] = a0.w;
            out[(ch0 + 4) * NPIX + pix] = a1.x;
            out[(ch0 + 5) * NPIX + pix] = a1.y;
            out[(ch0 + 6) * NPIX + pix] = a1.z;
            out[(ch0 + 7) * NPIX + pix] = a1.w;
        }
    }
}

// ---------------------------------------------------------------------------
// Fallback without workspace: direct per-sample fp32 gathers from (bc,h,w).
// ---------------------------------------------------------------------------
__global__ __launch_bounds__(256) void epi_gather_direct(const float* __restrict__ x,
                                                         const float* __restrict__ F,
                                                         float* __restrict__ out) {
    int tid  = blockIdx.x * 256 + threadIdx.x;
    int quad = tid & 3;
    int pix  = tid >> 2;

    LineGeom g = make_geom(F, pix);

    float4 acc = make_float4(0.f, 0.f, 0.f, 0.f);
    int base = quad * 4;

#pragma unroll 2
    for (int s = 0; s < 256; ++s) {
        int  yi    = chainY(g, s);
        bool valid = ((unsigned)yi < 256u);
        int  tcl   = valid ? yi : 0;
        int  addr  = g.col ? (tcl * WSZ + s) : (s * WSZ + tcl);
        if (valid) {
            acc.x += x[(base + 0) * NPIX + addr];
            acc.y += x[(base + 1) * NPIX + addr];
            acc.z += x[(base + 2) * NPIX + addr];
            acc.w += x[(base + 3) * NPIX + addr];
        }
    }

    out[(base + 0) * NPIX + pix] = acc.x;
    out[(base + 1) * NPIX + pix] = acc.y;
    out[(base + 2) * NPIX + pix] = acc.z;
    out[(base + 3) * NPIX + pix] = acc.w;
}

extern "C" void kernel_launch(void* const* d_in, const int* in_sizes, int n_in,
                              void* d_out, int out_size, void* d_ws, size_t ws_size,
                              hipStream_t stream) {
    const float* x   = (const float*)d_in[0];
    const float* F   = (const float*)d_in[1];
    float*       out = (float*)d_out;

    const size_t need = (size_t)NELEM * sizeof(__half) + 512;
    if (ws_size >= need) {
        __half* T = (__half*)d_ws;
        const uint4* Tq = (const uint4*)T;
        transpose_f16<<<NPIX / 256, 256, 0, stream>>>(x, T);
        // probe 1: VALU/issue floor (loads pinned to pad), x8 for visibility
        epi_gather_f16<8, true><<<(NPIX * 16) / 256, 256, 0, stream>>>(Tq, x, F, out);
        // probe 2 (runs LAST => correct final output): real gather x2
        epi_gather_f16<2, false><<<(NPIX * 16) / 256, 256, 0, stream>>>(Tq, x, F, out);
    } else {
        epi_gather_direct<<<(NPIX * 4) / 256, 256, 0, stream>>>(x, F, out);
    }
}

// Round 9
// 85.837 us; speedup vs baseline: 2.0280x; 2.0280x over previous
//
#include <hip/hip_runtime.h>
#include <hip/hip_fp16.h>

// x: (2,8,256,256) fp32, F: 3x3 fp32.
#define HS 256
#define WSZ 256
#define NPIX (HS * WSZ)        // 65536 pixels
#define NCH 16                 // B*C
#define NELEM (NPIX * NCH)     // half elements in T

typedef float f4 __attribute__((ext_vector_type(4)));

// ---------------------------------------------------------------------------
// Transpose + fp16 quantize: (bc, h, w) f32 -> (h, w, bc) f16, LDS-tiled,
// coalesced both sides. Also zeroes a 512 B pad at T[NELEM..).
// ---------------------------------------------------------------------------
__global__ __launch_bounds__(256) void transpose_f16(const float* __restrict__ x,
                                                     __half* __restrict__ T) {
    __shared__ float lds[16][257];   // +1 pad
    int tid  = threadIdx.x;
    int base = blockIdx.x * 256;
#pragma unroll
    for (int ch = 0; ch < 16; ++ch)
        lds[ch][tid] = x[ch * NPIX + base + tid];   // coalesced 1KB per instr
    if (blockIdx.x == 0 && tid < 128)
        ((unsigned int*)(T + NELEM))[tid] = 0u;     // 512 B zero pad
    __syncthreads();
    uint2* T2 = (uint2*)T;           // 8 B = 4 halves = one channel-quad
#pragma unroll
    for (int it = 0; it < 4; ++it) {
        int idx = it * 256 + tid;    // 0..1023 uint2 of this tile
        int p   = idx >> 2;          // local pixel
        int q   = idx & 3;           // channel quad
        __half2 a = __floats2half2_rn(lds[q * 4 + 0][p], lds[q * 4 + 1][p]);
        __half2 b = __floats2half2_rn(lds[q * 4 + 2][p], lds[q * 4 + 3][p]);
        uint2 o;
        o.x = __builtin_bit_cast(unsigned int, a);
        o.y = __builtin_bit_cast(unsigned int, b);
        T2[base * 4 + idx] = o;      // contiguous 8B/lane -> coalesced
    }
}

// ---------------------------------------------------------------------------
// Geometry (bit-exact, verified): FMA-contracted einsum, f32. UNCHANGED.
// ---------------------------------------------------------------------------
struct LineGeom {
    float p, q, c;
    bool  col;
};

__device__ __forceinline__ LineGeom make_geom(const float* __restrict__ F, int pix) {
#pragma clang fp contract(off)
    int w = pix & (WSZ - 1);
    int h = pix >> 8;
    float u = (float)w, v = (float)h;
    float a = __builtin_fmaf(F[3], v, F[0] * u) + F[6];
    float b = __builtin_fmaf(F[4], v, F[1] * u) + F[7];
    float c = __builtin_fmaf(F[5], v, F[2] * u) + F[8];
    const float eps = 1e-8f;
    float bs = (fabsf(b) < eps) ? eps : b;
    float as = (fabsf(a) < eps) ? eps : a;
    LineGeom g;
    g.col = (fabsf(b) >= fabsf(a));
    g.p   = g.col ? a : b;
    g.q   = g.col ? bs : as;
    g.c   = c;
    return g;
}

// Exact chain (reference-bit-exact): t = fma(p,s,c); y = (-t)/q IEEE; rint.
__device__ __forceinline__ int chainY(const LineGeom& g, int s) {
#pragma clang fp contract(off)
    float t  = __builtin_fmaf(g.p, (float)s, g.c);
    float y  = (-t) / g.q;
    return (int)__builtin_rintf(y);
}

// Linear chain: yl = fma(m, Delta, ybase) where m = -p*rq, ybase =
// fma(m, sb, -c*rq). Error vs the exact chain: a rint-relevant flip needs
// |y|<=256, which (|m|<=1 in col mode, |Delta|,|sb|<=256) implies
// |ybase-origin y0| <= 512 and total |yl - y_exact_chain| <= ~3e-4.
// Guard band 1.5e-3 (5x margin) redirects to the EXACT reference divide
// -> rint result is bit-identical to chainY for ALL samples, any F.
__device__ __forceinline__ int chainL(const LineGeom& g, float m, float ybase,
                                      float df, int sfull) {
#pragma clang fp contract(off)
    float yl = __builtin_fmaf(m, df, ybase);
    float fr = yl - floorf(yl);
    if (__builtin_expect(fabsf(fr - 0.5f) < 1.5e-3f, 0)) {
        float num = __builtin_fmaf(-g.p, (float)sfull, -g.c);
        yl = num / g.q;                          // exact reference chain
    }
    return (int)__builtin_rintf(yl);
}

__device__ __forceinline__ __half2 bch2(unsigned int v) {
    return __builtin_bit_cast(__half2, v);
}

// DPP rotate-add within the 16-lane row (wait-free VALU).
template <int CTRL>
__device__ __forceinline__ float dpp_ror_add(float v) {
    int t = __builtin_amdgcn_mov_dpp(__builtin_bit_cast(int, v), CTRL, 0xf, 0xf, true);
    return v + __builtin_bit_cast(float, t);
}

template <int CTRL>
__device__ __forceinline__ void ror_add8(f4& a0, f4& a1) {
    a0.x = dpp_ror_add<CTRL>(a0.x);
    a0.y = dpp_ror_add<CTRL>(a0.y);
    a0.z = dpp_ror_add<CTRL>(a0.z);
    a0.w = dpp_ror_add<CTRL>(a0.w);
    a1.x = dpp_ror_add<CTRL>(a1.x);
    a1.y = dpp_ror_add<CTRL>(a1.y);
    a1.z = dpp_ror_add<CTRL>(a1.z);
    a1.w = dpp_ror_add<CTRL>(a1.w);
}

// ---------------------------------------------------------------------------
// Gather v7 (v5 memory shape, VALU floor trimmed per R8 probe: floor was
// 10.5us at VALUBusy 88%): 16 lanes/pixel = 8 sample-slots x 2 ch-halves;
// lane r=2k+h loads 16 B (8 ch, half h) of s = 64b+8j+k; pixel's 16 lanes
// cover 8 consecutive samples = 256 B contiguous per load.
// Cuts vs v5:
//  (a) chainL linear-fma chain (7 instr vs 10; exact-divide fallback in a
//      1.5e-3 half-integer guard band -> rint bit-identical);
//  (b) h-half select folded into address BASES (rbA = own j's, rbB =
//      partner j's; 2 adds/batch replaces 8 cndmask selects/batch).
// Addr (16B units): y<<9 + rb + 64h(own)/64(1-h)(swp) + 16i (load imm);
// invalid y redirects into the 512 B zero pad (compensated for the imm).
// ---------------------------------------------------------------------------
#define QUAD_BCAST(dst, src, ctrl)                                              \
    dst = __builtin_amdgcn_mov_dpp(src, ctrl, 0xf, 0xf, false)

__global__ __launch_bounds__(256) void epi_gather_f16(const uint4* __restrict__ Tq,
                                                      const float* __restrict__ x,
                                                      const float* __restrict__ F,
                                                      float* __restrict__ out) {
    int tid = blockIdx.x * 256 + threadIdx.x;
    int r   = tid & 15;          // lane-in-pixel, r = 2k + h
    int k   = r >> 1;            // sample phase: s ≡ k (mod 8)
    int h   = r & 1;             // channel half: ch 8h..8h+7
    int pix = tid >> 4;

    LineGeom g = make_geom(F, pix);
    f4 a0 = {0.f, 0.f, 0.f, 0.f};
    f4 a1 = {0.f, 0.f, 0.f, 0.f};

    if (g.col) {
        // refined reciprocal (1 rcp + 1 NR) and linear-chain bases
        float r0 = __builtin_amdgcn_rcpf(g.q);
        float rq = __builtin_fmaf(__builtin_fmaf(-g.q, r0, 1.0f), r0, r0);
        int   sb = (h << 5) + k;             // own chains: s = sb + 64b + 8i
        float m  = -g.p * rq;
        float y0 = -g.c * rq;
        float yb = __builtin_fmaf(m, (float)sb, y0);

        const int PADB  = NPIX * 2;          // T size in 16B units (= 131072)
        int  padr  = PADB + r;               // zero-pad slot for this lane
        int  rb    = r;                      // r + 128*b, incremented per batch
        int  hoffA = h << 6;                 // own-half j-offset (64h units)
        int  hoffB = 64 - hoffA;             // partner-half j-offset

#pragma unroll
        for (int bb = 0; bb < 2; ++bb) {
            // f16 partials live across TWO batches (16 samples per slot)
            __half2 zz = __floats2half2_rn(0.f, 0.f);
            __half2 s0 = zz, s1 = zz, s2 = zz, s3 = zz;

#pragma unroll
            for (int b2 = 0; b2 < 2; ++b2) {
                const int b = 2 * bb + b2;
                // 4 own chains (j = 4h+i), then swap with pair lane
                int yown[4], yswp[4];
#pragma unroll
                for (int i = 0; i < 4; ++i)
                    yown[i] = chainL(g, m, yb, (float)(64 * b + 8 * i),
                                     sb + 64 * b + 8 * i);
#pragma unroll
                for (int i = 0; i < 4; ++i) QUAD_BCAST(yswp[i], yown[i], 0xB1);

                int rbA = rb + hoffA, rbB = rb + hoffB;
                int aO[4], aS[4];
#pragma unroll
                for (int i = 0; i < 4; ++i) {
                    int vo = (int)((unsigned)yown[i] << 9) + rbA;
                    int vs = (int)((unsigned)yswp[i] << 9) + rbB;
                    aO[i] = ((unsigned)yown[i] < 256u) ? vo : (padr - 16 * i);
                    aS[i] = ((unsigned)yswp[i] < 256u) ? vs : (padr - 16 * i);
                }
                // batch-issue 8 independent 16B loads; +16i folds into imm
                uint4 v0 = Tq[aO[0] +  0];
                uint4 v1 = Tq[aO[1] + 16];
                uint4 v2 = Tq[aO[2] + 32];
                uint4 v3 = Tq[aO[3] + 48];
                uint4 v4 = Tq[aS[0] +  0];
                uint4 v5 = Tq[aS[1] + 16];
                uint4 v6 = Tq[aS[2] + 32];
                uint4 v7 = Tq[aS[3] + 48];

#define ACC(V)                                                                  \
                s0 = __hadd2(s0, bch2((V).x));                                  \
                s1 = __hadd2(s1, bch2((V).y));                                  \
                s2 = __hadd2(s2, bch2((V).z));                                  \
                s3 = __hadd2(s3, bch2((V).w));
                ACC(v0) ACC(v1) ACC(v2) ACC(v3) ACC(v4) ACC(v5) ACC(v6) ACC(v7)
#undef ACC
                rb += 128;
            }
            // fold the 2-batch f16 partials into f32 accumulators
            float2 f;
            f = __half22float2(s0); a0.x += f.x; a0.y += f.y;
            f = __half22float2(s1); a0.z += f.x; a0.w += f.y;
            f = __half22float2(s2); a1.x += f.x; a1.y += f.y;
            f = __half22float2(s3); a1.z += f.x; a1.w += f.y;
        }
    } else {
        // Row mode (never taken for this F; generic correctness): per-sample
        // exact gathers from x (fp32) for this lane's channel half.
        int ch0 = h * 8;
        for (int mm = 0; mm < 32; ++mm) {
            int s  = 8 * mm + k;
            int xi = chainY(g, s);
            if ((unsigned)xi < 256u) {
                int addr = s * WSZ + xi;
                a0.x += x[(ch0 + 0) * NPIX + addr];
                a0.y += x[(ch0 + 1) * NPIX + addr];
                a0.z += x[(ch0 + 2) * NPIX + addr];
                a0.w += x[(ch0 + 3) * NPIX + addr];
                a1.x += x[(ch0 + 4) * NPIX + addr];
                a1.y += x[(ch0 + 5) * NPIX + addr];
                a1.z += x[(ch0 + 6) * NPIX + addr];
                a1.w += x[(ch0 + 7) * NPIX + addr];
            }
        }
    }

    // reduce over the 8 sample-slots: DPP row_ror 8,4,2 (preserves lane bit0)
    ror_add8<0x128>(a0, a1);   // row_ror:8
    ror_add8<0x124>(a0, a1);   // row_ror:4
    ror_add8<0x122>(a0, a1);   // row_ror:2

    if ((r & 14) == 0) {                 // lanes r=0 (ch 0-7) and r=1 (ch 8-15)
        int ch0 = h * 8;
        out[(ch0 + 0) * NPIX + pix] = a0.x;
        out[(ch0 + 1) * NPIX + pix] = a0.y;
        out[(ch0 + 2) * NPIX + pix] = a0.z;
        out[(ch0 + 3) * NPIX + pix] = a0.w;
        out[(ch0 + 4) * NPIX + pix] = a1.x;
        out[(ch0 + 5) * NPIX + pix] = a1.y;
        out[(ch0 + 6) * NPIX + pix] = a1.z;
        out[(ch0 + 7) * NPIX + pix] = a1.w;
    }
}

// ---------------------------------------------------------------------------
// Fallback without workspace: direct per-sample fp32 gathers from (bc,h,w).
// ---------------------------------------------------------------------------
__global__ __launch_bounds__(256) void epi_gather_direct(const float* __restrict__ x,
                                                         const float* __restrict__ F,
                                                         float* __restrict__ out) {
    int tid  = blockIdx.x * 256 + threadIdx.x;
    int quad = tid & 3;
    int pix  = tid >> 2;

    LineGeom g = make_geom(F, pix);

    float4 acc = make_float4(0.f, 0.f, 0.f, 0.f);
    int base = quad * 4;

#pragma unroll 2
    for (int s = 0; s < 256; ++s) {
        int  yi    = chainY(g, s);
        bool valid = ((unsigned)yi < 256u);
        int  tcl   = valid ? yi : 0;
        int  addr  = g.col ? (tcl * WSZ + s) : (s * WSZ + tcl);
        if (valid) {
            acc.x += x[(base + 0) * NPIX + addr];
            acc.y += x[(base + 1) * NPIX + addr];
            acc.z += x[(base + 2) * NPIX + addr];
            acc.w += x[(base + 3) * NPIX + addr];
        }
    }

    out[(base + 0) * NPIX + pix] = acc.x;
    out[(base + 1) * NPIX + pix] = acc.y;
    out[(base + 2) * NPIX + pix] = acc.z;
    out[(base + 3) * NPIX + pix] = acc.w;
}

extern "C" void kernel_launch(void* const* d_in, const int* in_sizes, int n_in,
                              void* d_out, int out_size, void* d_ws, size_t ws_size,
                              hipStream_t stream) {
    const float* x   = (const float*)d_in[0];
    const float* F   = (const float*)d_in[1];
    float*       out = (float*)d_out;

    const size_t need = (size_t)NELEM * sizeof(__half) + 512;
    if (ws_size >= need) {
        __half* T = (__half*)d_ws;
        transpose_f16<<<NPIX / 256, 256, 0, stream>>>(x, T);
        epi_gather_f16<<<(NPIX * 16) / 256, 256, 0, stream>>>((const uint4*)T, x, F, out);
    } else {
        epi_gather_direct<<<(NPIX * 4) / 256, 256, 0, stream>>>(x, F, out);
    }
}

// Round 10
// 80.588 us; speedup vs baseline: 2.1601x; 1.0651x over previous
//
#include <hip/hip_runtime.h>
#include <hip/hip_fp16.h>

// x: (2,8,256,256) fp32, F: 3x3 fp32.
#define HS 256
#define WSZ 256
#define NPIX (HS * WSZ)        // 65536 pixels
#define NCH 16                 // B*C
#define NELEM (NPIX * NCH)     // half elements in T

typedef float f4 __attribute__((ext_vector_type(4)));

// ---------------------------------------------------------------------------
// Transpose + fp16 quantize: (bc, h, w) f32 -> (h, w, bc) f16, LDS-tiled,
// coalesced both sides. Geometry/rint decisions are unaffected (f32 from F);
// only sampled VALUES are RTN-quantized once here.
// Also zeroes a 512 B pad at T[NELEM..) — the invalid-sample redirect target.
// ---------------------------------------------------------------------------
__global__ __launch_bounds__(256) void transpose_f16(const float* __restrict__ x,
                                                     __half* __restrict__ T) {
    __shared__ float lds[16][257];   // +1 pad
    int tid  = threadIdx.x;
    int base = blockIdx.x * 256;
#pragma unroll
    for (int ch = 0; ch < 16; ++ch)
        lds[ch][tid] = x[ch * NPIX + base + tid];   // coalesced 1KB per instr
    if (blockIdx.x == 0 && tid < 128)
        ((unsigned int*)(T + NELEM))[tid] = 0u;     // 512 B zero pad
    __syncthreads();
    uint2* T2 = (uint2*)T;           // 8 B = 4 halves = one channel-quad
#pragma unroll
    for (int it = 0; it < 4; ++it) {
        int idx = it * 256 + tid;    // 0..1023 uint2 of this tile
        int p   = idx >> 2;          // local pixel
        int q   = idx & 3;           // channel quad
        __half2 a = __floats2half2_rn(lds[q * 4 + 0][p], lds[q * 4 + 1][p]);
        __half2 b = __floats2half2_rn(lds[q * 4 + 2][p], lds[q * 4 + 3][p]);
        uint2 o;
        o.x = __builtin_bit_cast(unsigned int, a);
        o.y = __builtin_bit_cast(unsigned int, b);
        T2[base * 4 + idx] = o;      // contiguous 8B/lane -> coalesced
    }
}

// ---------------------------------------------------------------------------
// Geometry (bit-exact, verified): FMA-contracted einsum, f32. UNCHANGED.
// ---------------------------------------------------------------------------
struct LineGeom {
    float p, q, c;
    bool  col;
};

__device__ __forceinline__ LineGeom make_geom(const float* __restrict__ F, int pix) {
#pragma clang fp contract(off)
    int w = pix & (WSZ - 1);
    int h = pix >> 8;
    float u = (float)w, v = (float)h;
    float a = __builtin_fmaf(F[3], v, F[0] * u) + F[6];
    float b = __builtin_fmaf(F[4], v, F[1] * u) + F[7];
    float c = __builtin_fmaf(F[5], v, F[2] * u) + F[8];
    const float eps = 1e-8f;
    float bs = (fabsf(b) < eps) ? eps : b;
    float as = (fabsf(a) < eps) ? eps : a;
    LineGeom g;
    g.col = (fabsf(b) >= fabsf(a));
    g.p   = g.col ? a : b;
    g.q   = g.col ? bs : as;
    g.c   = c;
    return g;
}

// Exact chain (reference-bit-exact): t = fma(p,s,c); y = (-t)/q IEEE; rint.
// Used by row-mode and the direct fallback kernel.
__device__ __forceinline__ int chainY(const LineGeom& g, int s) {
#pragma clang fp contract(off)
    float t  = __builtin_fmaf(g.p, (float)s, g.c);
    float y  = (-t) / g.q;
    return (int)__builtin_rintf(y);
}

// Fast chain (verified R5-pass): rcp + 1 Newton + Markstein. |y1 - IEEE_div|
// <= ~1.5 ulp (<= 4.6e-5 for |y| < 512). A rint flip vs the exact chain
// requires y within that of a half-integer; detector |frac-0.5| < 2e-4
// (4x margin) redirects those rare lanes (~4e-4/sample) to the true IEEE
// divide. => rint result is bit-identical to chainY for ALL samples.
// NOTE R9 lesson: widening this band to 1.5e-3 (to enable a cheaper linear
// chain) REGRESSED 5.7us — wave-anylane fallback rate goes 2.5%->18%/chain.
// This 2e-4 band + per-sample Markstein chain is the measured optimum.
__device__ __forceinline__ int chainY_fast(const LineGeom& g, float rq, int s) {
#pragma clang fp contract(off)
    float num = __builtin_fmaf(-g.p, (float)s, -g.c);   // == -fma(p,s,c) exactly
    float y0  = num * rq;
    float e   = __builtin_fmaf(-g.q, y0, num);
    float y1  = __builtin_fmaf(e, rq, y0);
    float fr  = y1 - floorf(y1);
    if (__builtin_expect(fabsf(fr - 0.5f) < 2e-4f, 0))
        y1 = num / g.q;                                  // exact IEEE fallback
    return (int)__builtin_rintf(y1);
}

__device__ __forceinline__ __half2 bch2(unsigned int v) {
    return __builtin_bit_cast(__half2, v);
}

// DPP rotate-add within the 16-lane row (no LDS, no lgkm waits).
// CTRL must be a compile-time constant (builtin requirement) -> template.
template <int CTRL>
__device__ __forceinline__ float dpp_ror_add(float v) {
    int t = __builtin_amdgcn_mov_dpp(__builtin_bit_cast(int, v), CTRL, 0xf, 0xf, true);
    return v + __builtin_bit_cast(float, t);
}

template <int CTRL>
__device__ __forceinline__ void ror_add8(f4& a0, f4& a1) {
    a0.x = dpp_ror_add<CTRL>(a0.x);
    a0.y = dpp_ror_add<CTRL>(a0.y);
    a0.z = dpp_ror_add<CTRL>(a0.z);
    a0.w = dpp_ror_add<CTRL>(a0.w);
    a1.x = dpp_ror_add<CTRL>(a1.x);
    a1.y = dpp_ror_add<CTRL>(a1.y);
    a1.z = dpp_ror_add<CTRL>(a1.z);
    a1.w = dpp_ror_add<CTRL>(a1.w);
}

// ---------------------------------------------------------------------------
// Gather v5 — the session's measured optimum (80.1 us total, verified).
// 16 lanes/pixel = 8 sample-slots x 2 channel-halves; lane r=2k+h loads 16 B
// (8 ch, half h) of s = 8m+k; a pixel's 16 lanes cover 8 consecutive samples
// = 256 B contiguous per load. Balanced profile (R8 probe): VALU floor
// 10.5us @ 88% busy vs ~20us real => ~50% issue / ~50% latency; attacks on
// either side alone (R1 bytes, R2 lines, R9 instrs, R6 occupancy, R7
// algorithm) were null or regressions.
// ---------------------------------------------------------------------------
#define QUAD_BCAST(dst, src, ctrl)                                              \
    dst = __builtin_amdgcn_mov_dpp(src, ctrl, 0xf, 0xf, false)

__global__ __launch_bounds__(256) void epi_gather_f16(const uint4* __restrict__ Tq,
                                                      const float* __restrict__ x,
                                                      const float* __restrict__ F,
                                                      float* __restrict__ out) {
    int tid = blockIdx.x * 256 + threadIdx.x;
    int r   = tid & 15;          // lane-in-pixel, r = 2k + h
    int k   = r >> 1;            // sample phase: s ≡ k (mod 8)
    int h   = r & 1;             // channel half: ch 8h..8h+7
    int pix = tid >> 4;

    LineGeom g = make_geom(F, pix);
    f4 a0 = {0.f, 0.f, 0.f, 0.f};
    f4 a1 = {0.f, 0.f, 0.f, 0.f};

    if (g.col) {
        // per-pixel reciprocal for the fast chain (1 rcp + 1 NR step)
        float r0 = __builtin_amdgcn_rcpf(g.q);
        float rq = __builtin_fmaf(__builtin_fmaf(-g.q, r0, 1.0f), r0, r0);

        const int PADB = NPIX * 2;      // T size in 16B units (= 131072)
        int  padr = PADB + r;           // zero-pad slot for this lane
        int  rb   = r;                  // r + 128*b, incremented per batch
        bool hb   = (h != 0);
        int  sb   = (h << 5) + k;       // own chains: s = sb + 64b + 8i

#pragma unroll
        for (int bb = 0; bb < 2; ++bb) {
            // f16 partials live across TWO batches (16 samples max per slot)
            __half2 zz = __floats2half2_rn(0.f, 0.f);
            __half2 s0 = zz, s1 = zz, s2 = zz, s3 = zz;

#pragma unroll
            for (int b2 = 0; b2 < 2; ++b2) {
                int b = 2 * bb + b2;
                // 4 own chains (jj = 4h+i), then swap with pair lane
                int yown[4], yswp[4];
#pragma unroll
                for (int i = 0; i < 4; ++i)
                    yown[i] = chainY_fast(g, rq, sb + 64 * b + 8 * i);
#pragma unroll
                for (int i = 0; i < 4; ++i) QUAD_BCAST(yswp[i], yown[i], 0xB1);

                int adr[8];
#pragma unroll
                for (int i = 0; i < 4; ++i) {
                    int ylo = hb ? yswp[i] : yown[i];   // chain of j = i
                    int yhi = hb ? yown[i] : yswp[i];   // chain of j = i+4
                    int alo = (int)((unsigned)ylo << 9) + rb;
                    int ahi = (int)((unsigned)yhi << 9) + rb;
                    adr[i]     = ((unsigned)ylo < 256u) ? alo : (padr - 16 * i);
                    adr[i + 4] = ((unsigned)yhi < 256u) ? ahi : (padr - 16 * (i + 4));
                }
                // batch-issue 8 independent 16B loads; +16j folds into imm
                uint4 v0 = Tq[adr[0] +   0];
                uint4 v1 = Tq[adr[1] +  16];
                uint4 v2 = Tq[adr[2] +  32];
                uint4 v3 = Tq[adr[3] +  48];
                uint4 v4 = Tq[adr[4] +  64];
                uint4 v5 = Tq[adr[5] +  80];
                uint4 v6 = Tq[adr[6] +  96];
                uint4 v7 = Tq[adr[7] + 112];

#define ACC(V)                                                                  \
                s0 = __hadd2(s0, bch2((V).x));                                  \
                s1 = __hadd2(s1, bch2((V).y));                                  \
                s2 = __hadd2(s2, bch2((V).z));                                  \
                s3 = __hadd2(s3, bch2((V).w));
                ACC(v0) ACC(v1) ACC(v2) ACC(v3) ACC(v4) ACC(v5) ACC(v6) ACC(v7)
#undef ACC
                rb += 128;
            }
            // fold the 2-batch f16 partials into f32 accumulators
            float2 f;
            f = __half22float2(s0); a0.x += f.x; a0.y += f.y;
            f = __half22float2(s1); a0.z += f.x; a0.w += f.y;
            f = __half22float2(s2); a1.x += f.x; a1.y += f.y;
            f = __half22float2(s3); a1.z += f.x; a1.w += f.y;
        }
    } else {
        // Row mode (never taken for this F; generic correctness): per-sample
        // scalar gathers from x (fp32) for this lane's channel half.
        int ch0 = h * 8;
        for (int m = 0; m < 32; ++m) {
            int s  = 8 * m + k;
            int xi = chainY(g, s);
            if ((unsigned)xi < 256u) {
                int addr = s * WSZ + xi;
                a0.x += x[(ch0 + 0) * NPIX + addr];
                a0.y += x[(ch0 + 1) * NPIX + addr];
                a0.z += x[(ch0 + 2) * NPIX + addr];
                a0.w += x[(ch0 + 3) * NPIX + addr];
                a1.x += x[(ch0 + 4) * NPIX + addr];
                a1.y += x[(ch0 + 5) * NPIX + addr];
                a1.z += x[(ch0 + 6) * NPIX + addr];
                a1.w += x[(ch0 + 7) * NPIX + addr];
            }
        }
    }

    // reduce over the 8 sample-slots: DPP row_ror 8,4,2 (preserves lane bit0,
    // sums all 8 same-parity slots; wait-free VALU, no LDS)
    ror_add8<0x128>(a0, a1);   // row_ror:8
    ror_add8<0x124>(a0, a1);   // row_ror:4
    ror_add8<0x122>(a0, a1);   // row_ror:2

    if ((r & 14) == 0) {                 // lanes r=0 (ch 0-7) and r=1 (ch 8-15)
        int ch0 = h * 8;
        out[(ch0 + 0) * NPIX + pix] = a0.x;
        out[(ch0 + 1) * NPIX + pix] = a0.y;
        out[(ch0 + 2) * NPIX + pix] = a0.z;
        out[(ch0 + 3) * NPIX + pix] = a0.w;
        out[(ch0 + 4) * NPIX + pix] = a1.x;
        out[(ch0 + 5) * NPIX + pix] = a1.y;
        out[(ch0 + 6) * NPIX + pix] = a1.z;
        out[(ch0 + 7) * NPIX + pix] = a1.w;
    }
}

// ---------------------------------------------------------------------------
// Fallback without workspace: direct per-sample fp32 gathers from (bc,h,w).
// ---------------------------------------------------------------------------
__global__ __launch_bounds__(256) void epi_gather_direct(const float* __restrict__ x,
                                                         const float* __restrict__ F,
                                                         float* __restrict__ out) {
    int tid  = blockIdx.x * 256 + threadIdx.x;
    int quad = tid & 3;
    int pix  = tid >> 2;

    LineGeom g = make_geom(F, pix);

    float4 acc = make_float4(0.f, 0.f, 0.f, 0.f);
    int base = quad * 4;

#pragma unroll 2
    for (int s = 0; s < 256; ++s) {
        int  yi    = chainY(g, s);
        bool valid = ((unsigned)yi < 256u);
        int  tcl   = valid ? yi : 0;
        int  addr  = g.col ? (tcl * WSZ + s) : (s * WSZ + tcl);
        if (valid) {
            acc.x += x[(base + 0) * NPIX + addr];
            acc.y += x[(base + 1) * NPIX + addr];
            acc.z += x[(base + 2) * NPIX + addr];
            acc.w += x[(base + 3) * NPIX + addr];
        }
    }

    out[(base + 0) * NPIX + pix] = acc.x;
    out[(base + 1) * NPIX + pix] = acc.y;
    out[(base + 2) * NPIX + pix] = acc.z;
    out[(base + 3) * NPIX + pix] = acc.w;
}

extern "C" void kernel_launch(void* const* d_in, const int* in_sizes, int n_in,
                              void* d_out, int out_size, void* d_ws, size_t ws_size,
                              hipStream_t stream) {
    const float* x   = (const float*)d_in[0];
    const float* F   = (const float*)d_in[1];
    float*       out = (float*)d_out;

    const size_t need = (size_t)NELEM * sizeof(__half) + 512;
    if (ws_size >= need) {
        __half* T = (__half*)d_ws;
        transpose_f16<<<NPIX / 256, 256, 0, stream>>>(x, T);
        epi_gather_f16<<<(NPIX * 16) / 256, 256, 0, stream>>>((const uint4*)T, x, F, out);
    } else {
        epi_gather_direct<<<(NPIX * 4) / 256, 256, 0, stream>>>(x, F, out);
    }
}